// Round 3
// baseline (1566.807 us; speedup 1.0000x reference)
//
#include <hip/hip_runtime.h>

// out[b,o] = sum_g as[b,g]*ws[o,g]*dot(x4[b,g*128..],w4[o,..]) + bias[o]
// B=4096, O=11008, K=4096, GS=128, G=32. Inputs normalized by harness to f32.
// R7: 256x256 tile, 512 threads, 8 waves (2m x 4n), wave tile 128x64 (the
//     proven 256^2 quadrant geometry; 1.33x better LDS intensity than 64x64).
//     BK=128 (= one scale group), dbuf LDS 132KB, 1 block/CU.
//     Per-tile IMMEDIATE rescale: each i-iteration = {ds_read next A-frags ||
//     8 MFMA || 48 rescale VALU} so matrix and VALU pipes interleave within
//     each wave instead of alternating in 2600-cy phases. Scales staged via
//     LDS (waves 0/1, global_load_lds). One __syncthreads per group; next
//     group's stage issued right after -> full-group prefetch in flight.

#define B_DIM 4096
#define O_DIM 11008
#define K_DIM 4096
#define G_NUM 32

#define NX32 8388608u    // int32 elements of xq
#define NW32 22544384u   // int32 elements of wq
#define X8_BYTES  16777216u
#define W8_BYTES  45088768u

typedef int   i32x4 __attribute__((ext_vector_type(4)));
typedef float f32x4 __attribute__((ext_vector_type(4)));

#define GLOAD16(src, dst) __builtin_amdgcn_global_load_lds(                      \
    (const __attribute__((address_space(1))) void*)(src),                        \
    (__attribute__((address_space(3))) void*)(dst), 16, 0, 0)

// ---------------- prepass 1: unpack nibbles -> signed int8 ----------------
__device__ __forceinline__ unsigned pack2(int v) {
    int t = v ^ 0x88;                                  // (q^8)-8 per nibble
    unsigned lo = (unsigned)(((t & 15) - 8) & 0xFF);
    unsigned hi = (unsigned)((((t >> 4) & 15) - 8) & 0xFF);
    return lo | (hi << 8);
}

__global__ __launch_bounds__(256)
void unpack_kernel(const int* __restrict__ xq, const int* __restrict__ wq,
                   unsigned char* __restrict__ X8, unsigned char* __restrict__ W8) {
    unsigned t = blockIdx.x * 256u + threadIdx.x;      // one thread: 8 int32 -> 16 B
    const int* src;
    unsigned char* dst;
    if (t < NX32 / 8) {
        src = xq + (size_t)t * 8;
        dst = X8 + (size_t)t * 16;
    } else {
        unsigned j = t - NX32 / 8;
        src = wq + (size_t)j * 8;
        dst = W8 + (size_t)j * 16;
    }
    int4 v0 = ((const int4*)src)[0];
    int4 v1 = ((const int4*)src)[1];
    uint4 o;
    o.x = pack2(v0.x) | (pack2(v0.y) << 16);
    o.y = pack2(v0.z) | (pack2(v0.w) << 16);
    o.z = pack2(v1.x) | (pack2(v1.y) << 16);
    o.w = pack2(v1.z) | (pack2(v1.w) << 16);
    *(uint4*)dst = o;
}

// ------------- prepass 2: coalesced LDS-tiled scale transpose -------------
__global__ __launch_bounds__(256)
void tscale_kernel(const float* __restrict__ as_, const float* __restrict__ ws_,
                   float* __restrict__ asT, float* __restrict__ wsT) {
    __shared__ float tile[64][33];
    const int blk = blockIdx.x, t = threadIdx.x;
    const float* src; float* dst; int R0, RTOT;
    if (blk < 64) { src = as_; dst = asT; R0 = blk * 64;        RTOT = B_DIM; }
    else          { src = ws_; dst = wsT; R0 = (blk - 64) * 64; RTOT = O_DIM; }
    {
        const int r = t >> 2, cc = (t & 3) * 8;
        const float* p = src + (size_t)(R0 + r) * G_NUM + cc;
        f32x4 v0 = *(const f32x4*)p;
        f32x4 v1 = *(const f32x4*)(p + 4);
#pragma unroll
        for (int k = 0; k < 4; ++k) { tile[r][cc + k] = v0[k]; tile[r][cc + 4 + k] = v1[k]; }
    }
    __syncthreads();
    {
        const int g = t >> 3, bc = (t & 7) * 8;
        f32x4 w0, w1;
#pragma unroll
        for (int k = 0; k < 4; ++k) { w0[k] = tile[bc + k][g]; w1[k] = tile[bc + 4 + k][g]; }
        float* q = dst + (size_t)g * RTOT + R0 + bc;
        *(f32x4*)q = w0;
        *(f32x4*)(q + 4) = w1;
    }
}

// ---------------- GEMM: 256x256 tile, 512 threads ----------------
__global__ __launch_bounds__(512, 2)
void gemm_i8(const unsigned char* __restrict__ X8, const unsigned char* __restrict__ W8,
             const float* __restrict__ asT, const float* __restrict__ wsT,
             const float* __restrict__ bias, float* __restrict__ out) {
    __shared__ __align__(16) unsigned char A0[32768];
    __shared__ __align__(16) unsigned char B0[32768];
    __shared__ __align__(16) unsigned char A1[32768];
    __shared__ __align__(16) unsigned char B1[32768];
    __shared__ __align__(16) float SA0[256];
    __shared__ __align__(16) float SW0[256];
    __shared__ __align__(16) float SA1[256];
    __shared__ __align__(16) float SW1[256];

    const int tid  = threadIdx.x;
    const int wv   = tid >> 6;
    const int lane = tid & 63;
    const int quad = lane >> 4;
    const int lq   = lane & 15;
    const int bm   = blockIdx.x;           // 16
    const int bn   = blockIdx.y;           // 43
    const int wm   = (wv & 1) << 7;        // 0 / 128
    const int wn   = (wv >> 1) << 6;       // 0 / 64 / 128 / 192

    f32x4 facc[8][4] = {};

    const size_t xrow0 = (size_t)(bm * 256) * K_DIM;
    const size_t wrow0 = (size_t)(bn * 256) * K_DIM;
    const int pa0 = ((quad ^ (lq & 7)) << 4);
    const int pa1 = (((4 + quad) ^ (lq & 7)) << 4);

    const int r8 = tid >> 3;               // 0..63 (global row-in-pass)
    const int c8 = tid & 7;
    const int sw = ((c8 ^ (r8 & 7)) << 4); // source-side XOR swizzle
    const int ldsw = (wv << 10);           // wave-uniform LDS base within pass

    auto stageAB = [&](int g, unsigned char* Ad, unsigned char* Bd) {  // 8 vm ops
        const int gb = g << 7;
#pragma unroll
        for (int p = 0; p < 4; ++p) {
            const int row = (p << 6) + r8;
            GLOAD16(X8 + xrow0 + (size_t)row * K_DIM + gb + sw, Ad + (p << 13) + ldsw);
        }
#pragma unroll
        for (int p = 0; p < 4; ++p) {
            const int row = (p << 6) + r8;
            GLOAD16(W8 + wrow0 + (size_t)row * K_DIM + gb + sw, Bd + (p << 13) + ldsw);
        }
    };
    auto stageScales = [&](int g, float* sAn, float* sWn) {
        if (wv == 0) {
            GLOAD16(asT + (size_t)g * B_DIM + bm * 256 + (lane << 2), sAn);
        } else if (wv == 1) {
            GLOAD16(wsT + (size_t)g * O_DIM + bn * 256 + (lane << 2), sWn);
        }
    };

    // body for one K-group: consumes cur buffers, prefetches gnext into nxt.
    auto body = [&](int gnext,
                    const unsigned char* Ac, const unsigned char* Bc,
                    const float* sAc, const float* sWc,
                    unsigned char* An, unsigned char* Bn, float* sAn, float* sWn) {
        __syncthreads();                    // drains stage(cur)+scales(cur)
        stageAB(gnext, An, Bn);             // in flight for the whole group
        stageScales(gnext, sAn, sWn);

        // current-group B fragments + W scales
        i32x4 bv0[4], bv1[4];
        float wsn[4];
#pragma unroll
        for (int j = 0; j < 4; ++j) {
            bv0[j] = *(const i32x4*)&Bc[((wn + (j << 4) + lq) << 7) + pa0];
            bv1[j] = *(const i32x4*)&Bc[((wn + (j << 4) + lq) << 7) + pa1];
            wsn[j] = sWc[wn + (j << 4) + lq];
        }
        // preload i=0 A-frags + A-scale
        i32x4 a0c = *(const i32x4*)&Ac[((wm + lq) << 7) + pa0];
        i32x4 a1c = *(const i32x4*)&Ac[((wm + lq) << 7) + pa1];
        f32x4 sac = *(const f32x4*)&sAc[wm + (quad << 2)];

#pragma unroll
        for (int i = 0; i < 8; ++i) {
            asm volatile("s_waitcnt lgkmcnt(0)" ::: "memory");
            __builtin_amdgcn_sched_barrier(0);
            const i32x4 a0 = a0c, a1 = a1c;
            const f32x4 sa = sac;
            if (i < 7) {                    // prefetch next m-row; flies under MFMA
                a0c = *(const i32x4*)&Ac[((wm + ((i + 1) << 4) + lq) << 7) + pa0];
                a1c = *(const i32x4*)&Ac[((wm + ((i + 1) << 4) + lq) << 7) + pa1];
                sac = *(const f32x4*)&sAc[wm + ((i + 1) << 4) + (quad << 2)];
            }
            i32x4 q[4];
            __builtin_amdgcn_s_setprio(1);
#pragma unroll
            for (int j = 0; j < 4; ++j)
                q[j] = __builtin_amdgcn_mfma_i32_16x16x64_i8(a0, bv0[j], (i32x4){0, 0, 0, 0}, 0, 0, 0);
#pragma unroll
            for (int j = 0; j < 4; ++j)
                q[j] = __builtin_amdgcn_mfma_i32_16x16x64_i8(a1, bv1[j], q[j], 0, 0, 0);
            __builtin_amdgcn_s_setprio(0);
            // immediate rescale of this i-row (overlaps MFMA drain)
#pragma unroll
            for (int j = 0; j < 4; ++j) {
                const f32x4 s = sa * wsn[j];
                f32x4 gf;
#pragma unroll
                for (int r = 0; r < 4; ++r) gf[r] = (float)q[j][r];
                facc[i][j] += gf * s;
            }
        }
    };

    // prologue: stage group 0
    stageAB(0, A0, B0);
    stageScales(0, SA0, SW0);

#pragma unroll 1
    for (int g2 = 0; g2 < G_NUM; g2 += 2) {
        const int gn2 = (g2 + 2 < G_NUM) ? g2 + 2 : G_NUM - 1;  // clamp tail
        body(g2 + 1, A0, B0, SA0, SW0, A1, B1, SA1, SW1);
        body(gn2,    A1, B1, SA1, SW1, A0, B0, SA0, SW0);
    }

    // epilogue (f32 output); C/D: col=lq, row=quad*4+r
    const int n0 = bn * 256 + wn + lq;
    const int m0 = bm * 256 + wm + (quad << 2);
    float bvs[4];
#pragma unroll
    for (int j = 0; j < 4; ++j) bvs[j] = bias[n0 + (j << 4)];
#pragma unroll
    for (int i = 0; i < 8; ++i) {
#pragma unroll
        for (int r = 0; r < 4; ++r) {
            float* orow = out + (size_t)(m0 + (i << 4) + r) * O_DIM;
#pragma unroll
            for (int j = 0; j < 4; ++j)
                orow[n0 + (j << 4)] = facc[i][j][r] + bvs[j];
        }
    }
}

extern "C" void kernel_launch(void* const* d_in, const int* in_sizes, int n_in,
                              void* d_out, int out_size, void* d_ws, size_t ws_size,
                              hipStream_t stream) {
    const int*   xq   = (const int*)d_in[0];
    const float* as_  = (const float*)d_in[1];
    const int*   wq   = (const int*)d_in[2];
    const float* ws_  = (const float*)d_in[3];
    const float* bias = (const float*)d_in[4];
    float* out        = (float*)d_out;

    unsigned char* X8 = (unsigned char*)d_ws;
    unsigned char* W8 = X8 + X8_BYTES;
    float* asT = (float*)((unsigned char*)d_ws + X8_BYTES + W8_BYTES);
    float* wsT = asT + (size_t)G_NUM * B_DIM;

    unpack_kernel<<<(NX32 + NW32) / 8 / 256, 256, 0, stream>>>(xq, wq, X8, W8);
    tscale_kernel<<<64 + 172, 256, 0, stream>>>(as_, ws_, asT, wsT);
    gemm_i8<<<dim3(B_DIM / 256, O_DIM / 256), 512, 0, stream>>>(X8, W8, asT, wsT, bias, out);
}

// Round 4
// 1554.459 us; speedup vs baseline: 1.0079x; 1.0079x over previous
//
#include <hip/hip_runtime.h>

// out[b,o] = sum_g as[b,g]*ws[o,g]*dot(x4[b,g*128..],w4[o,..]) + bias[o]
// B=4096, O=11008, K=4096, GS=128, G=32. Inputs normalized by harness to f32.
// R8: R7 geometry (256x256 tile, 512 thr, 8 waves, wave tile 128x64, BK=128,
//     dbuf 132KB LDS, per-tile immediate rescale) with ONE fix:
//     __launch_bounds__(512, 1). Empirical finding from R3: hipcc treats the
//     2nd launch_bounds arg as min BLOCKS/CU (CUDA semantics) -> (512,2) gave
//     a 128-VGPR cap (4 waves/SIMD target) and 2.2GB of scratch spill
//     (WRITE_SIZE 2.38GB, MfmaUtil 5.5%). (512,1) -> 256-VGPR budget; live
//     set ~220 fits with zero spill. LDS 132KB limits to 1 block/CU anyway.

#define B_DIM 4096
#define O_DIM 11008
#define K_DIM 4096
#define G_NUM 32

#define NX32 8388608u    // int32 elements of xq
#define NW32 22544384u   // int32 elements of wq
#define X8_BYTES  16777216u
#define W8_BYTES  45088768u

typedef int   i32x4 __attribute__((ext_vector_type(4)));
typedef float f32x4 __attribute__((ext_vector_type(4)));

#define GLOAD16(src, dst) __builtin_amdgcn_global_load_lds(                      \
    (const __attribute__((address_space(1))) void*)(src),                        \
    (__attribute__((address_space(3))) void*)(dst), 16, 0, 0)

// ---------------- prepass 1: unpack nibbles -> signed int8 ----------------
__device__ __forceinline__ unsigned pack2(int v) {
    int t = v ^ 0x88;                                  // (q^8)-8 per nibble
    unsigned lo = (unsigned)(((t & 15) - 8) & 0xFF);
    unsigned hi = (unsigned)((((t >> 4) & 15) - 8) & 0xFF);
    return lo | (hi << 8);
}

__global__ __launch_bounds__(256)
void unpack_kernel(const int* __restrict__ xq, const int* __restrict__ wq,
                   unsigned char* __restrict__ X8, unsigned char* __restrict__ W8) {
    unsigned t = blockIdx.x * 256u + threadIdx.x;      // one thread: 8 int32 -> 16 B
    const int* src;
    unsigned char* dst;
    if (t < NX32 / 8) {
        src = xq + (size_t)t * 8;
        dst = X8 + (size_t)t * 16;
    } else {
        unsigned j = t - NX32 / 8;
        src = wq + (size_t)j * 8;
        dst = W8 + (size_t)j * 16;
    }
    int4 v0 = ((const int4*)src)[0];
    int4 v1 = ((const int4*)src)[1];
    uint4 o;
    o.x = pack2(v0.x) | (pack2(v0.y) << 16);
    o.y = pack2(v0.z) | (pack2(v0.w) << 16);
    o.z = pack2(v1.x) | (pack2(v1.y) << 16);
    o.w = pack2(v1.z) | (pack2(v1.w) << 16);
    *(uint4*)dst = o;
}

// ------------- prepass 2: coalesced LDS-tiled scale transpose -------------
__global__ __launch_bounds__(256)
void tscale_kernel(const float* __restrict__ as_, const float* __restrict__ ws_,
                   float* __restrict__ asT, float* __restrict__ wsT) {
    __shared__ float tile[64][33];
    const int blk = blockIdx.x, t = threadIdx.x;
    const float* src; float* dst; int R0, RTOT;
    if (blk < 64) { src = as_; dst = asT; R0 = blk * 64;        RTOT = B_DIM; }
    else          { src = ws_; dst = wsT; R0 = (blk - 64) * 64; RTOT = O_DIM; }
    {
        const int r = t >> 2, cc = (t & 3) * 8;
        const float* p = src + (size_t)(R0 + r) * G_NUM + cc;
        f32x4 v0 = *(const f32x4*)p;
        f32x4 v1 = *(const f32x4*)(p + 4);
#pragma unroll
        for (int k = 0; k < 4; ++k) { tile[r][cc + k] = v0[k]; tile[r][cc + 4 + k] = v1[k]; }
    }
    __syncthreads();
    {
        const int g = t >> 3, bc = (t & 7) * 8;
        f32x4 w0, w1;
#pragma unroll
        for (int k = 0; k < 4; ++k) { w0[k] = tile[bc + k][g]; w1[k] = tile[bc + 4 + k][g]; }
        float* q = dst + (size_t)g * RTOT + R0 + bc;
        *(f32x4*)q = w0;
        *(f32x4*)(q + 4) = w1;
    }
}

// ---------------- GEMM: 256x256 tile, 512 threads ----------------
__global__ __launch_bounds__(512, 1)
void gemm_i8(const unsigned char* __restrict__ X8, const unsigned char* __restrict__ W8,
             const float* __restrict__ asT, const float* __restrict__ wsT,
             const float* __restrict__ bias, float* __restrict__ out) {
    __shared__ __align__(16) unsigned char A0[32768];
    __shared__ __align__(16) unsigned char B0[32768];
    __shared__ __align__(16) unsigned char A1[32768];
    __shared__ __align__(16) unsigned char B1[32768];
    __shared__ __align__(16) float SA0[256];
    __shared__ __align__(16) float SW0[256];
    __shared__ __align__(16) float SA1[256];
    __shared__ __align__(16) float SW1[256];

    const int tid  = threadIdx.x;
    const int wv   = tid >> 6;
    const int lane = tid & 63;
    const int quad = lane >> 4;
    const int lq   = lane & 15;
    const int bm   = blockIdx.x;           // 16
    const int bn   = blockIdx.y;           // 43
    const int wm   = (wv & 1) << 7;        // 0 / 128
    const int wn   = (wv >> 1) << 6;       // 0 / 64 / 128 / 192

    f32x4 facc[8][4] = {};

    const size_t xrow0 = (size_t)(bm * 256) * K_DIM;
    const size_t wrow0 = (size_t)(bn * 256) * K_DIM;
    const int pa0 = ((quad ^ (lq & 7)) << 4);
    const int pa1 = (((4 + quad) ^ (lq & 7)) << 4);

    const int r8 = tid >> 3;               // 0..63 (global row-in-pass)
    const int c8 = tid & 7;
    const int sw = ((c8 ^ (r8 & 7)) << 4); // source-side XOR swizzle
    const int ldsw = (wv << 10);           // wave-uniform LDS base within pass

    auto stageAB = [&](int g, unsigned char* Ad, unsigned char* Bd) {  // 8 vm ops
        const int gb = g << 7;
#pragma unroll
        for (int p = 0; p < 4; ++p) {
            const int row = (p << 6) + r8;
            GLOAD16(X8 + xrow0 + (size_t)row * K_DIM + gb + sw, Ad + (p << 13) + ldsw);
        }
#pragma unroll
        for (int p = 0; p < 4; ++p) {
            const int row = (p << 6) + r8;
            GLOAD16(W8 + wrow0 + (size_t)row * K_DIM + gb + sw, Bd + (p << 13) + ldsw);
        }
    };
    auto stageScales = [&](int g, float* sAn, float* sWn) {
        if (wv == 0) {
            GLOAD16(asT + (size_t)g * B_DIM + bm * 256 + (lane << 2), sAn);
        } else if (wv == 1) {
            GLOAD16(wsT + (size_t)g * O_DIM + bn * 256 + (lane << 2), sWn);
        }
    };

    // body for one K-group: consumes cur buffers, prefetches gnext into nxt.
    auto body = [&](int gnext,
                    const unsigned char* Ac, const unsigned char* Bc,
                    const float* sAc, const float* sWc,
                    unsigned char* An, unsigned char* Bn, float* sAn, float* sWn) {
        __syncthreads();                    // drains stage(cur)+scales(cur)
        stageAB(gnext, An, Bn);             // in flight for the whole group
        stageScales(gnext, sAn, sWn);

        // current-group B fragments + W scales
        i32x4 bv0[4], bv1[4];
        float wsn[4];
#pragma unroll
        for (int j = 0; j < 4; ++j) {
            bv0[j] = *(const i32x4*)&Bc[((wn + (j << 4) + lq) << 7) + pa0];
            bv1[j] = *(const i32x4*)&Bc[((wn + (j << 4) + lq) << 7) + pa1];
            wsn[j] = sWc[wn + (j << 4) + lq];
        }
        // preload i=0 A-frags + A-scale
        i32x4 a0c = *(const i32x4*)&Ac[((wm + lq) << 7) + pa0];
        i32x4 a1c = *(const i32x4*)&Ac[((wm + lq) << 7) + pa1];
        f32x4 sac = *(const f32x4*)&sAc[wm + (quad << 2)];

#pragma unroll
        for (int i = 0; i < 8; ++i) {
            asm volatile("s_waitcnt lgkmcnt(0)" ::: "memory");
            __builtin_amdgcn_sched_barrier(0);
            const i32x4 a0 = a0c, a1 = a1c;
            const f32x4 sa = sac;
            if (i < 7) {                    // prefetch next m-row; flies under MFMA
                a0c = *(const i32x4*)&Ac[((wm + ((i + 1) << 4) + lq) << 7) + pa0];
                a1c = *(const i32x4*)&Ac[((wm + ((i + 1) << 4) + lq) << 7) + pa1];
                sac = *(const f32x4*)&sAc[wm + ((i + 1) << 4) + (quad << 2)];
            }
            i32x4 q[4];
            __builtin_amdgcn_s_setprio(1);
#pragma unroll
            for (int j = 0; j < 4; ++j)
                q[j] = __builtin_amdgcn_mfma_i32_16x16x64_i8(a0, bv0[j], (i32x4){0, 0, 0, 0}, 0, 0, 0);
#pragma unroll
            for (int j = 0; j < 4; ++j)
                q[j] = __builtin_amdgcn_mfma_i32_16x16x64_i8(a1, bv1[j], q[j], 0, 0, 0);
            __builtin_amdgcn_s_setprio(0);
            // immediate rescale of this i-row (overlaps MFMA drain)
#pragma unroll
            for (int j = 0; j < 4; ++j) {
                const f32x4 s = sa * wsn[j];
                f32x4 gf;
#pragma unroll
                for (int r = 0; r < 4; ++r) gf[r] = (float)q[j][r];
                facc[i][j] += gf * s;
            }
        }
    };

    // prologue: stage group 0
    stageAB(0, A0, B0);
    stageScales(0, SA0, SW0);

#pragma unroll 1
    for (int g2 = 0; g2 < G_NUM; g2 += 2) {
        const int gn2 = (g2 + 2 < G_NUM) ? g2 + 2 : G_NUM - 1;  // clamp tail
        body(g2 + 1, A0, B0, SA0, SW0, A1, B1, SA1, SW1);
        body(gn2,    A1, B1, SA1, SW1, A0, B0, SA0, SW0);
    }

    // epilogue (f32 output); C/D: col=lq, row=quad*4+r
    const int n0 = bn * 256 + wn + lq;
    const int m0 = bm * 256 + wm + (quad << 2);
    float bvs[4];
#pragma unroll
    for (int j = 0; j < 4; ++j) bvs[j] = bias[n0 + (j << 4)];
#pragma unroll
    for (int i = 0; i < 8; ++i) {
#pragma unroll
        for (int r = 0; r < 4; ++r) {
            float* orow = out + (size_t)(m0 + (i << 4) + r) * O_DIM;
#pragma unroll
            for (int j = 0; j < 4; ++j)
                orow[n0 + (j << 4)] = facc[i][j][r] + bvs[j];
        }
    }
}

extern "C" void kernel_launch(void* const* d_in, const int* in_sizes, int n_in,
                              void* d_out, int out_size, void* d_ws, size_t ws_size,
                              hipStream_t stream) {
    const int*   xq   = (const int*)d_in[0];
    const float* as_  = (const float*)d_in[1];
    const int*   wq   = (const int*)d_in[2];
    const float* ws_  = (const float*)d_in[3];
    const float* bias = (const float*)d_in[4];
    float* out        = (float*)d_out;

    unsigned char* X8 = (unsigned char*)d_ws;
    unsigned char* W8 = X8 + X8_BYTES;
    float* asT = (float*)((unsigned char*)d_ws + X8_BYTES + W8_BYTES);
    float* wsT = asT + (size_t)G_NUM * B_DIM;

    unpack_kernel<<<(NX32 + NW32) / 8 / 256, 256, 0, stream>>>(xq, wq, X8, W8);
    tscale_kernel<<<64 + 172, 256, 0, stream>>>(as_, ws_, asT, wsT);
    gemm_i8<<<dim3(B_DIM / 256, O_DIM / 256), 512, 0, stream>>>(X8, W8, asT, wsT, bias, out);
}

// Round 5
// 1524.434 us; speedup vs baseline: 1.0278x; 1.0197x over previous
//
#include <hip/hip_runtime.h>

// out[b,o] = sum_g as[b,g]*ws[o,g]*dot(x4[b,g*128..],w4[o,..]) + bias[o]
// B=4096, O=11008, K=4096, GS=128, G=32. Inputs normalized by harness to f32.
// R9: R7/R8 geometry (256x256 tile, 512 thr, 8 waves, wave tile 128x64,
//     BK=128, dbuf 132KB LDS, per-tile immediate rescale). Register-budget
//     fix attempt #2: __launch_bounds__ 2nd arg did NOT raise the 128-VGPR
//     cap (R8 == R3 bit-identical counters). Switch to the raw AMDGPU
//     attributes the backend consumes:
//       amdgpu_flat_work_group_size(512,512) + amdgpu_waves_per_eu(2,2)
//     -> 2 waves/SIMD target -> 256-VGPR cap; live set ~220 fits, no spill.

#define B_DIM 4096
#define O_DIM 11008
#define K_DIM 4096
#define G_NUM 32

#define NX32 8388608u    // int32 elements of xq
#define NW32 22544384u   // int32 elements of wq
#define X8_BYTES  16777216u
#define W8_BYTES  45088768u

typedef int   i32x4 __attribute__((ext_vector_type(4)));
typedef float f32x4 __attribute__((ext_vector_type(4)));

#define GLOAD16(src, dst) __builtin_amdgcn_global_load_lds(                      \
    (const __attribute__((address_space(1))) void*)(src),                        \
    (__attribute__((address_space(3))) void*)(dst), 16, 0, 0)

// ---------------- prepass 1: unpack nibbles -> signed int8 ----------------
__device__ __forceinline__ unsigned pack2(int v) {
    int t = v ^ 0x88;                                  // (q^8)-8 per nibble
    unsigned lo = (unsigned)(((t & 15) - 8) & 0xFF);
    unsigned hi = (unsigned)((((t >> 4) & 15) - 8) & 0xFF);
    return lo | (hi << 8);
}

__global__ __launch_bounds__(256)
void unpack_kernel(const int* __restrict__ xq, const int* __restrict__ wq,
                   unsigned char* __restrict__ X8, unsigned char* __restrict__ W8) {
    unsigned t = blockIdx.x * 256u + threadIdx.x;      // one thread: 8 int32 -> 16 B
    const int* src;
    unsigned char* dst;
    if (t < NX32 / 8) {
        src = xq + (size_t)t * 8;
        dst = X8 + (size_t)t * 16;
    } else {
        unsigned j = t - NX32 / 8;
        src = wq + (size_t)j * 8;
        dst = W8 + (size_t)j * 16;
    }
    int4 v0 = ((const int4*)src)[0];
    int4 v1 = ((const int4*)src)[1];
    uint4 o;
    o.x = pack2(v0.x) | (pack2(v0.y) << 16);
    o.y = pack2(v0.z) | (pack2(v0.w) << 16);
    o.z = pack2(v1.x) | (pack2(v1.y) << 16);
    o.w = pack2(v1.z) | (pack2(v1.w) << 16);
    *(uint4*)dst = o;
}

// ------------- prepass 2: coalesced LDS-tiled scale transpose -------------
__global__ __launch_bounds__(256)
void tscale_kernel(const float* __restrict__ as_, const float* __restrict__ ws_,
                   float* __restrict__ asT, float* __restrict__ wsT) {
    __shared__ float tile[64][33];
    const int blk = blockIdx.x, t = threadIdx.x;
    const float* src; float* dst; int R0, RTOT;
    if (blk < 64) { src = as_; dst = asT; R0 = blk * 64;        RTOT = B_DIM; }
    else          { src = ws_; dst = wsT; R0 = (blk - 64) * 64; RTOT = O_DIM; }
    {
        const int r = t >> 2, cc = (t & 3) * 8;
        const float* p = src + (size_t)(R0 + r) * G_NUM + cc;
        f32x4 v0 = *(const f32x4*)p;
        f32x4 v1 = *(const f32x4*)(p + 4);
#pragma unroll
        for (int k = 0; k < 4; ++k) { tile[r][cc + k] = v0[k]; tile[r][cc + 4 + k] = v1[k]; }
    }
    __syncthreads();
    {
        const int g = t >> 3, bc = (t & 7) * 8;
        f32x4 w0, w1;
#pragma unroll
        for (int k = 0; k < 4; ++k) { w0[k] = tile[bc + k][g]; w1[k] = tile[bc + 4 + k][g]; }
        float* q = dst + (size_t)g * RTOT + R0 + bc;
        *(f32x4*)q = w0;
        *(f32x4*)(q + 4) = w1;
    }
}

// ---------------- GEMM: 256x256 tile, 512 threads ----------------
__global__
__attribute__((amdgpu_flat_work_group_size(512, 512)))
__attribute__((amdgpu_waves_per_eu(2, 2)))
void gemm_i8(const unsigned char* __restrict__ X8, const unsigned char* __restrict__ W8,
             const float* __restrict__ asT, const float* __restrict__ wsT,
             const float* __restrict__ bias, float* __restrict__ out) {
    __shared__ __align__(16) unsigned char A0[32768];
    __shared__ __align__(16) unsigned char B0[32768];
    __shared__ __align__(16) unsigned char A1[32768];
    __shared__ __align__(16) unsigned char B1[32768];
    __shared__ __align__(16) float SA0[256];
    __shared__ __align__(16) float SW0[256];
    __shared__ __align__(16) float SA1[256];
    __shared__ __align__(16) float SW1[256];

    const int tid  = threadIdx.x;
    const int wv   = tid >> 6;
    const int lane = tid & 63;
    const int quad = lane >> 4;
    const int lq   = lane & 15;
    const int bm   = blockIdx.x;           // 16
    const int bn   = blockIdx.y;           // 43
    const int wm   = (wv & 1) << 7;        // 0 / 128
    const int wn   = (wv >> 1) << 6;       // 0 / 64 / 128 / 192

    f32x4 facc[8][4] = {};

    const size_t xrow0 = (size_t)(bm * 256) * K_DIM;
    const size_t wrow0 = (size_t)(bn * 256) * K_DIM;
    const int pa0 = ((quad ^ (lq & 7)) << 4);
    const int pa1 = (((4 + quad) ^ (lq & 7)) << 4);

    const int r8 = tid >> 3;               // 0..63 (global row-in-pass)
    const int c8 = tid & 7;
    const int sw = ((c8 ^ (r8 & 7)) << 4); // source-side XOR swizzle
    const int ldsw = (wv << 10);           // wave-uniform LDS base within pass

    auto stageAB = [&](int g, unsigned char* Ad, unsigned char* Bd) {  // 8 vm ops
        const int gb = g << 7;
#pragma unroll
        for (int p = 0; p < 4; ++p) {
            const int row = (p << 6) + r8;
            GLOAD16(X8 + xrow0 + (size_t)row * K_DIM + gb + sw, Ad + (p << 13) + ldsw);
        }
#pragma unroll
        for (int p = 0; p < 4; ++p) {
            const int row = (p << 6) + r8;
            GLOAD16(W8 + wrow0 + (size_t)row * K_DIM + gb + sw, Bd + (p << 13) + ldsw);
        }
    };
    auto stageScales = [&](int g, float* sAn, float* sWn) {
        if (wv == 0) {
            GLOAD16(asT + (size_t)g * B_DIM + bm * 256 + (lane << 2), sAn);
        } else if (wv == 1) {
            GLOAD16(wsT + (size_t)g * O_DIM + bn * 256 + (lane << 2), sWn);
        }
    };

    // body for one K-group: consumes cur buffers, prefetches gnext into nxt.
    auto body = [&](int gnext,
                    const unsigned char* Ac, const unsigned char* Bc,
                    const float* sAc, const float* sWc,
                    unsigned char* An, unsigned char* Bn, float* sAn, float* sWn) {
        __syncthreads();                    // drains stage(cur)+scales(cur)
        stageAB(gnext, An, Bn);             // in flight for the whole group
        stageScales(gnext, sAn, sWn);

        // current-group B fragments + W scales
        i32x4 bv0[4], bv1[4];
        float wsn[4];
#pragma unroll
        for (int j = 0; j < 4; ++j) {
            bv0[j] = *(const i32x4*)&Bc[((wn + (j << 4) + lq) << 7) + pa0];
            bv1[j] = *(const i32x4*)&Bc[((wn + (j << 4) + lq) << 7) + pa1];
            wsn[j] = sWc[wn + (j << 4) + lq];
        }
        // preload i=0 A-frags + A-scale
        i32x4 a0c = *(const i32x4*)&Ac[((wm + lq) << 7) + pa0];
        i32x4 a1c = *(const i32x4*)&Ac[((wm + lq) << 7) + pa1];
        f32x4 sac = *(const f32x4*)&sAc[wm + (quad << 2)];

#pragma unroll
        for (int i = 0; i < 8; ++i) {
            asm volatile("s_waitcnt lgkmcnt(0)" ::: "memory");
            __builtin_amdgcn_sched_barrier(0);
            const i32x4 a0 = a0c, a1 = a1c;
            const f32x4 sa = sac;
            if (i < 7) {                    // prefetch next m-row; flies under MFMA
                a0c = *(const i32x4*)&Ac[((wm + ((i + 1) << 4) + lq) << 7) + pa0];
                a1c = *(const i32x4*)&Ac[((wm + ((i + 1) << 4) + lq) << 7) + pa1];
                sac = *(const f32x4*)&sAc[wm + ((i + 1) << 4) + (quad << 2)];
            }
            i32x4 q[4];
            __builtin_amdgcn_s_setprio(1);
#pragma unroll
            for (int j = 0; j < 4; ++j)
                q[j] = __builtin_amdgcn_mfma_i32_16x16x64_i8(a0, bv0[j], (i32x4){0, 0, 0, 0}, 0, 0, 0);
#pragma unroll
            for (int j = 0; j < 4; ++j)
                q[j] = __builtin_amdgcn_mfma_i32_16x16x64_i8(a1, bv1[j], q[j], 0, 0, 0);
            __builtin_amdgcn_s_setprio(0);
            // immediate rescale of this i-row (overlaps MFMA drain)
#pragma unroll
            for (int j = 0; j < 4; ++j) {
                const f32x4 s = sa * wsn[j];
                f32x4 gf;
#pragma unroll
                for (int r = 0; r < 4; ++r) gf[r] = (float)q[j][r];
                facc[i][j] += gf * s;
            }
        }
    };

    // prologue: stage group 0
    stageAB(0, A0, B0);
    stageScales(0, SA0, SW0);

#pragma unroll 1
    for (int g2 = 0; g2 < G_NUM; g2 += 2) {
        const int gn2 = (g2 + 2 < G_NUM) ? g2 + 2 : G_NUM - 1;  // clamp tail
        body(g2 + 1, A0, B0, SA0, SW0, A1, B1, SA1, SW1);
        body(gn2,    A1, B1, SA1, SW1, A0, B0, SA0, SW0);
    }

    // epilogue (f32 output); C/D: col=lq, row=quad*4+r
    const int n0 = bn * 256 + wn + lq;
    const int m0 = bm * 256 + wm + (quad << 2);
    float bvs[4];
#pragma unroll
    for (int j = 0; j < 4; ++j) bvs[j] = bias[n0 + (j << 4)];
#pragma unroll
    for (int i = 0; i < 8; ++i) {
#pragma unroll
        for (int r = 0; r < 4; ++r) {
            float* orow = out + (size_t)(m0 + (i << 4) + r) * O_DIM;
#pragma unroll
            for (int j = 0; j < 4; ++j)
                orow[n0 + (j << 4)] = facc[i][j][r] + bvs[j];
        }
    }
}

extern "C" void kernel_launch(void* const* d_in, const int* in_sizes, int n_in,
                              void* d_out, int out_size, void* d_ws, size_t ws_size,
                              hipStream_t stream) {
    const int*   xq   = (const int*)d_in[0];
    const float* as_  = (const float*)d_in[1];
    const int*   wq   = (const int*)d_in[2];
    const float* ws_  = (const float*)d_in[3];
    const float* bias = (const float*)d_in[4];
    float* out        = (float*)d_out;

    unsigned char* X8 = (unsigned char*)d_ws;
    unsigned char* W8 = X8 + X8_BYTES;
    float* asT = (float*)((unsigned char*)d_ws + X8_BYTES + W8_BYTES);
    float* wsT = asT + (size_t)G_NUM * B_DIM;

    unpack_kernel<<<(NX32 + NW32) / 8 / 256, 256, 0, stream>>>(xq, wq, X8, W8);
    tscale_kernel<<<64 + 172, 256, 0, stream>>>(as_, ws_, asT, wsT);
    gemm_i8<<<dim3(B_DIM / 256, O_DIM / 256), 512, 0, stream>>>(X8, W8, asT, wsT, bias, out);
}

// Round 6
// 523.852 us; speedup vs baseline: 2.9909x; 2.9100x over previous
//
#include <hip/hip_runtime.h>

// out[b,o] = sum_g as[b,g]*ws[o,g]*dot(x4[b,g*128..],w4[o,..]) + bias[o]
// B=4096, O=11008, K=4096, GS=128, G=32. Inputs normalized by harness to f32.
// R10: back to the PROVEN R4 envelope (128x128 tile, 256 thr, 4 waves,
//      64x64 wave tile, dbuf 64KB LDS, dim3(32,86), launch_bounds(256,2),
//      VGPR 128 + AGPR accumulators, no spill). ONE change vs R4:
//      immediate per-i-row rescale. Instead of {32 MFMA -> gacc[4][4](64 AGPR);
//      then 192-inst VALU rescale}, each of 4 i-iterations does
//      {8 MFMA -> q[4] (16 AGPR); 48 VALU rescale} -- iteration i+1's MFMAs
//      are independent of i's rescale, so matrix and VALU pipes interleave
//      within each wave instead of alternating in ~600-cy phases.
//      256^2 geometry abandoned: its f32 facc (128 regs) must be ARCH VGPRs
//      and the arch cap is 128 (R3/R4/R5: three occupancy directives all
//      ignored; spill 2.2GB). No asm waitcnt/sched pins (R6: 328 > R4: 304).

#define B_DIM 4096
#define O_DIM 11008
#define K_DIM 4096
#define G_NUM 32

#define NX32 8388608u    // int32 elements of xq
#define NW32 22544384u   // int32 elements of wq
#define X8_BYTES  16777216u
#define W8_BYTES  45088768u

typedef int   i32x4 __attribute__((ext_vector_type(4)));
typedef float f32x4 __attribute__((ext_vector_type(4)));

// ---------------- prepass 1: unpack nibbles -> signed int8 ----------------
__device__ __forceinline__ unsigned pack2(int v) {
    int t = v ^ 0x88;                                  // (q^8)-8 per nibble
    unsigned lo = (unsigned)(((t & 15) - 8) & 0xFF);
    unsigned hi = (unsigned)((((t >> 4) & 15) - 8) & 0xFF);
    return lo | (hi << 8);
}

__global__ __launch_bounds__(256)
void unpack_kernel(const int* __restrict__ xq, const int* __restrict__ wq,
                   unsigned char* __restrict__ X8, unsigned char* __restrict__ W8) {
    unsigned t = blockIdx.x * 256u + threadIdx.x;      // one thread: 8 int32 -> 16 B
    const int* src;
    unsigned char* dst;
    if (t < NX32 / 8) {
        src = xq + (size_t)t * 8;
        dst = X8 + (size_t)t * 16;
    } else {
        unsigned j = t - NX32 / 8;
        src = wq + (size_t)j * 8;
        dst = W8 + (size_t)j * 16;
    }
    int4 v0 = ((const int4*)src)[0];
    int4 v1 = ((const int4*)src)[1];
    uint4 o;
    o.x = pack2(v0.x) | (pack2(v0.y) << 16);
    o.y = pack2(v0.z) | (pack2(v0.w) << 16);
    o.z = pack2(v1.x) | (pack2(v1.y) << 16);
    o.w = pack2(v1.z) | (pack2(v1.w) << 16);
    *(uint4*)dst = o;
}

// ------------- prepass 2: coalesced LDS-tiled scale transpose -------------
__global__ __launch_bounds__(256)
void tscale_kernel(const float* __restrict__ as_, const float* __restrict__ ws_,
                   float* __restrict__ asT, float* __restrict__ wsT) {
    __shared__ float tile[64][33];
    const int blk = blockIdx.x, t = threadIdx.x;
    const float* src; float* dst; int R0, RTOT;
    if (blk < 64) { src = as_; dst = asT; R0 = blk * 64;        RTOT = B_DIM; }
    else          { src = ws_; dst = wsT; R0 = (blk - 64) * 64; RTOT = O_DIM; }
    {
        const int r = t >> 2, cc = (t & 3) * 8;
        const float* p = src + (size_t)(R0 + r) * G_NUM + cc;
        f32x4 v0 = *(const f32x4*)p;
        f32x4 v1 = *(const f32x4*)(p + 4);
#pragma unroll
        for (int k = 0; k < 4; ++k) { tile[r][cc + k] = v0[k]; tile[r][cc + 4 + k] = v1[k]; }
    }
    __syncthreads();
    {
        const int g = t >> 3, bc = (t & 7) * 8;
        f32x4 w0, w1;
#pragma unroll
        for (int k = 0; k < 4; ++k) { w0[k] = tile[bc + k][g]; w1[k] = tile[bc + 4 + k][g]; }
        float* q = dst + (size_t)g * RTOT + R0 + bc;
        *(f32x4*)q = w0;
        *(f32x4*)(q + 4) = w1;
    }
}

// ---------------- GEMM ----------------
__global__ __launch_bounds__(256, 2)
void gemm_i8(const unsigned char* __restrict__ X8, const unsigned char* __restrict__ W8,
             const float* __restrict__ asT, const float* __restrict__ wsT,
             const float* __restrict__ bias, float* __restrict__ out) {
    __shared__ __align__(16) unsigned char A0[16384];
    __shared__ __align__(16) unsigned char B0[16384];
    __shared__ __align__(16) unsigned char A1[16384];
    __shared__ __align__(16) unsigned char B1[16384];

    const int tid  = threadIdx.x;
    const int wv   = tid >> 6;
    const int lane = tid & 63;
    const int quad = lane >> 4;
    const int lq   = lane & 15;
    const int bm   = blockIdx.x;
    const int bn   = blockIdx.y;
    const int wm   = (wv & 1) << 6;
    const int wn   = (wv >> 1) << 6;

    f32x4 facc[4][4] = {};

    const int l8 = lane >> 3;
    const int c8 = lane & 7;
    const int sw_chunk = ((c8 ^ l8) << 4);            // XOR store-side swizzle
    const size_t xrow0 = (size_t)(bm * 128) * K_DIM;
    const size_t wrow0 = (size_t)(bn * 128) * K_DIM;
    const int abase = bm * 128 + wm + (quad << 2);
    const int wbase = bn * 128 + wn + lq;
    const int pa0 = ((quad ^ (lq & 7)) << 4);
    const int pa1 = (((4 + quad) ^ (lq & 7)) << 4);

    auto stage = [&](int g, unsigned char* Ad, unsigned char* Bd) {
        const int gb = g << 7;
#pragma unroll
        for (int s = 0; s < 4; ++s) {
            const int slab = (wv << 2) + s;
            const int row  = (slab << 3) + l8;
            const unsigned char* gpA = X8 + xrow0 + (size_t)row * K_DIM + gb + sw_chunk;
            const unsigned char* gpB = W8 + wrow0 + (size_t)row * K_DIM + gb + sw_chunk;
            __builtin_amdgcn_global_load_lds(
                (const __attribute__((address_space(1))) void*)gpA,
                (__attribute__((address_space(3))) void*)(Ad + (slab << 10)), 16, 0, 0);
            __builtin_amdgcn_global_load_lds(
                (const __attribute__((address_space(1))) void*)gpB,
                (__attribute__((address_space(3))) void*)(Bd + (slab << 10)), 16, 0, 0);
        }
    };

    auto compute = [&](int g, const unsigned char* Ab, const unsigned char* Bb) {
        // scales: issued here, first consumed after ~8 MFMAs (latency hidden)
        f32x4 asr[4];
        float wsn[4];
#pragma unroll
        for (int i = 0; i < 4; ++i)
            asr[i] = *(const f32x4*)&asT[(g << 12) + abase + (i << 4)];
#pragma unroll
        for (int j = 0; j < 4; ++j)
            wsn[j] = wsT[(size_t)g * O_DIM + wbase + (j << 4)];

        // B fragments for both k-slices (live across the i-loop)
        i32x4 bv0[4], bv1[4];
#pragma unroll
        for (int j = 0; j < 4; ++j) {
            bv0[j] = *(const i32x4*)&Bb[((wn + (j << 4) + lq) << 7) + pa0];
            bv1[j] = *(const i32x4*)&Bb[((wn + (j << 4) + lq) << 7) + pa1];
        }
        // preload i=0 A fragments
        i32x4 a0c = *(const i32x4*)&Ab[((wm + lq) << 7) + pa0];
        i32x4 a1c = *(const i32x4*)&Ab[((wm + lq) << 7) + pa1];

#pragma unroll
        for (int i = 0; i < 4; ++i) {
            const i32x4 a0 = a0c, a1 = a1c;
            if (i < 3) {                    // prefetch next i-row under MFMA
                a0c = *(const i32x4*)&Ab[((wm + ((i + 1) << 4) + lq) << 7) + pa0];
                a1c = *(const i32x4*)&Ab[((wm + ((i + 1) << 4) + lq) << 7) + pa1];
            }
            i32x4 q[4];
#pragma unroll
            for (int j = 0; j < 4; ++j)
                q[j] = __builtin_amdgcn_mfma_i32_16x16x64_i8(a0, bv0[j], (i32x4){0, 0, 0, 0}, 0, 0, 0);
#pragma unroll
            for (int j = 0; j < 4; ++j)
                q[j] = __builtin_amdgcn_mfma_i32_16x16x64_i8(a1, bv1[j], q[j], 0, 0, 0);
            // immediate rescale of this i-row: independent of i+1's MFMAs,
            // so the VALU here overlaps the next MFMA cluster.
#pragma unroll
            for (int j = 0; j < 4; ++j) {
                const f32x4 s = asr[i] * wsn[j];
                f32x4 gf;
#pragma unroll
                for (int r = 0; r < 4; ++r) gf[r] = (float)q[j][r];
                facc[i][j] += gf * s;
            }
        }
    };

    stage(0, A0, B0);

    for (int g2 = 0; g2 < G_NUM; g2 += 2) {
        __syncthreads();                     // drains stage(g2) — issued a full phase ago
        stage(g2 + 1, A1, B1);               // flies during compute(g2)
        compute(g2, A0, B0);

        __syncthreads();                     // drains stage(g2+1) — issued a phase ago
        if (g2 + 2 < G_NUM) stage(g2 + 2, A0, B0);
        compute(g2 + 1, A1, B1);
    }

    // epilogue (f32 output); C/D: col=lq, row=quad*4+r
    const int n0 = bn * 128 + wn + lq;
    const int m0 = bm * 128 + wm + (quad << 2);
    float bvs[4];
#pragma unroll
    for (int j = 0; j < 4; ++j) bvs[j] = bias[n0 + (j << 4)];
#pragma unroll
    for (int i = 0; i < 4; ++i) {
#pragma unroll
        for (int r = 0; r < 4; ++r) {
            float* orow = out + (size_t)(m0 + (i << 4) + r) * O_DIM;
#pragma unroll
            for (int j = 0; j < 4; ++j)
                orow[n0 + (j << 4)] = facc[i][j][r] + bvs[j];
        }
    }
}

extern "C" void kernel_launch(void* const* d_in, const int* in_sizes, int n_in,
                              void* d_out, int out_size, void* d_ws, size_t ws_size,
                              hipStream_t stream) {
    const int*   xq   = (const int*)d_in[0];
    const float* as_  = (const float*)d_in[1];
    const int*   wq   = (const int*)d_in[2];
    const float* ws_  = (const float*)d_in[3];
    const float* bias = (const float*)d_in[4];
    float* out        = (float*)d_out;

    unsigned char* X8 = (unsigned char*)d_ws;
    unsigned char* W8 = X8 + X8_BYTES;
    float* asT = (float*)((unsigned char*)d_ws + X8_BYTES + W8_BYTES);
    float* wsT = asT + (size_t)G_NUM * B_DIM;

    unpack_kernel<<<(NX32 + NW32) / 8 / 256, 256, 0, stream>>>(xq, wq, X8, W8);
    tscale_kernel<<<64 + 172, 256, 0, stream>>>(as_, ws_, asT, wsT);
    gemm_i8<<<dim3(B_DIM / 128, O_DIM / 128), 256, 0, stream>>>(X8, W8, asT, wsT, bias, out);
}